// Round 10
// baseline (164.888 us; speedup 1.0000x reference)
//
#include <hip/hip_runtime.h>
#include <hip/hip_bf16.h>
#include <math.h>

#define TT 4096
#define CC 1024
#define NH 16
#define HD 64

typedef unsigned short ushortT;
typedef __attribute__((ext_vector_type(8))) short short8;
typedef __attribute__((ext_vector_type(4))) float f32x4;

#define GLOAD_LDS16(gp, lp)                                                   \
    __builtin_amdgcn_global_load_lds(                                         \
        (const __attribute__((address_space(1))) void*)(gp),                  \
        (__attribute__((address_space(3))) void*)(lp), 16, 0, 0)

#define EXP2F(x) __builtin_amdgcn_exp2f(x)   // single v_exp_f32

__device__ __forceinline__ ushortT f2bf(float f) {
    __hip_bfloat16 h = __float2bfloat16(f);
    ushortT u; __builtin_memcpy(&u, &h, 2); return u;
}
__device__ __forceinline__ float bf2f(ushortT u) {
    return __uint_as_float(((unsigned)u) << 16);
}

// Partial slot: y bf16[64][64] (8192B) + m f32[64] (256B) + l f32[64] (256B)
#define PSLOT_BYTES 8704
// Chunking: qb 0..21 direct; 22..45 split2; 46..63 split3.
// Tickets/head = 54 (split3) + 48 (split2) + 22 (direct) = 124.
// Partial slots/head = 102 -> 16*102*8704 = 14.2MB < 14MB region.
#define NCHUNK_H 124
#define NTICK (NCHUNK_H * NH)

// ---------------------------------------------------------------------------
// One fused f32->bf16 conversion over x and the four weights.
// ---------------------------------------------------------------------------
__global__ __launch_bounds__(256) void cvt_all(
    const float* __restrict__ x,  const float* __restrict__ wq,
    const float* __restrict__ wk, const float* __restrict__ wv,
    const float* __restrict__ wo,
    ushortT* __restrict__ xb,  ushortT* __restrict__ wqb,
    ushortT* __restrict__ wkb, ushortT* __restrict__ wvb,
    ushortT* __restrict__ wob)
{
    const int i = (blockIdx.x * 256 + threadIdx.x) * 4;
    const int NX = TT * CC, NW = CC * CC;
    const float* s; ushortT* d; int off;
    if (i < NX)               { s = x;  d = xb;  off = i; }
    else if (i < NX + NW)     { s = wq; d = wqb; off = i - NX; }
    else if (i < NX + 2 * NW) { s = wk; d = wkb; off = i - NX - NW; }
    else if (i < NX + 3 * NW) { s = wv; d = wvb; off = i - NX - 2 * NW; }
    else                      { s = wo; d = wob; off = i - NX - 3 * NW; }
    float4 v = *(const float4*)(s + off);
    *(ushort4*)(d + off) = make_ushort4(f2bf(v.x), f2bf(v.y), f2bf(v.z), f2bf(v.w));
}

// ---------------------------------------------------------------------------
// Fused QKV GEMM: blockIdx.z selects weight + epilogue.
// z=0: Q = RoPE(x Wq^T) * 0.125*log2e -> bf16 [h][T][d]
// z=1: K = RoPE(x Wk^T)              -> bf16 [h][T][d]
// z=2: V^T slot-permuted: slot(k) = (k&32)|(((k>>2)&3)<<3)|(((k>>4)&1)<<2)|(k&3)
//      chosen so attention's register-P IS the PV A-fragment (no shuffles).
// ---------------------------------------------------------------------------
__global__ __launch_bounds__(256) void gemm_qkv(
    const ushortT* __restrict__ A,
    const ushortT* __restrict__ Bq, const ushortT* __restrict__ Bk,
    const ushortT* __restrict__ Bv,
    const float* __restrict__ fcos, const float* __restrict__ fsin,
    ushortT* __restrict__ q16, ushortT* __restrict__ k16,
    ushortT* __restrict__ vt16)
{
    __shared__ char lds[49152];            // 3 x (A 8KB + B 8KB)

    const int z = blockIdx.z;
    const ushortT* B = (z == 0) ? Bq : (z == 1) ? Bk : Bv;

    const int lin = (int)(blockIdx.y * gridDim.x + blockIdx.x);
    const int nwg8 = (int)((gridDim.x * gridDim.y) >> 3);
    const int swz = (lin & 7) * nwg8 + (lin >> 3);
    const int bm = (swz % (int)gridDim.x) * 128;
    const int bn = (swz / (int)gridDim.x) * 128;
    const int tid = threadIdx.x;
    const int w = tid >> 6, l = tid & 63;
    const int wm = w >> 1, wn = w & 1;

    f32x4 acc[4][4] = {};

    auto stageg = [&](int kk, int base) {
        #pragma unroll
        for (int e = 0; e < 2; ++e) {
            const int D = (w * 2 + e) * 1024 + l * 16;
            const int r = D >> 6;
            const int c = (D & 63) >> 1;
            GLOAD_LDS16(A + (size_t)(bm + r) * CC + kk + c, lds + base + (w * 2 + e) * 1024);
            GLOAD_LDS16(B + (size_t)(bn + r) * CC + kk + c, lds + base + 8192 + (w * 2 + e) * 1024);
        }
    };

    stageg(0, 0);
    stageg(32, 16384);

    for (int kt = 0; kt < 32; ++kt) {
        const int cur = kt % 3;
        if (kt + 2 < 32) {
            stageg((kt + 2) * 32, ((kt + 2) % 3) * 16384);
            asm volatile("s_waitcnt vmcnt(8)" ::: "memory");
        } else if (kt + 1 < 32) {
            asm volatile("s_waitcnt vmcnt(4)" ::: "memory");
        } else {
            asm volatile("s_waitcnt vmcnt(0)" ::: "memory");
        }
        __builtin_amdgcn_s_barrier();
        __builtin_amdgcn_sched_barrier(0);

        const ushortT* As = (const ushortT*)(lds + cur * 16384);
        const ushortT* Bs = (const ushortT*)(lds + cur * 16384 + 8192);

        short8 af[4], bfr[4];
        #pragma unroll
        for (int i = 0; i < 4; ++i) {
            int row = wm * 64 + i * 16 + (l & 15);
            af[i] = *(const short8*)(As + row * 32 + (l >> 4) * 8);
        }
        #pragma unroll
        for (int j = 0; j < 4; ++j) {
            int row = wn * 64 + j * 16 + (l & 15);
            bfr[j] = *(const short8*)(Bs + row * 32 + (l >> 4) * 8);
        }
        #pragma unroll
        for (int i = 0; i < 4; ++i)
            #pragma unroll
            for (int j = 0; j < 4; ++j)
                acc[i][j] = __builtin_amdgcn_mfma_f32_16x16x32_bf16(af[i], bfr[j], acc[i][j], 0, 0, 0);
        __builtin_amdgcn_s_barrier();
    }

    if (z < 2) {
        const float rsc = (z == 0) ? 0.18033688011112042f : 1.0f;  // 0.125*log2(e)
        ushortT* dq = (z == 0) ? q16 : k16;
        float* cs = (float*)lds;
        float* sn = (float*)(lds + 16384);
        for (int idx = tid; idx < 128 * 32; idx += 256) {
            int rr = idx >> 5, cc2 = idx & 31;
            cs[idx] = fcos[(size_t)(bm + rr) * 32 + cc2];
            sn[idx] = fsin[(size_t)(bm + rr) * 32 + cc2];
        }
        __syncthreads();
        #pragma unroll
        for (int i = 0; i < 4; ++i)
            #pragma unroll
            for (int j = 0; j < 4; ++j)
                #pragma unroll
                for (int r = 0; r < 4; ++r) {
                    const int lt = wm * 64 + i * 16 + (l >> 4) * 4 + r;
                    const int o = bn + wn * 64 + j * 16 + (l & 15);
                    const float v = acc[i][j][r];
                    const float p = __shfl_xor(v, 1);
                    const int pp = (o & 63) >> 1;
                    const float cv = cs[lt * 32 + pp], sv = sn[lt * 32 + pp];
                    const float outv = ((o & 1) ? (p * sv + v * cv) : (v * cv - p * sv)) * rsc;
                    const int t = bm + lt, head = o >> 6, dd = o & 63;
                    dq[((size_t)head * TT + t) * HD + dd] = f2bf(outv);
                }
    } else {
        #pragma unroll
        for (int i = 0; i < 4; ++i)
            #pragma unroll
            for (int j = 0; j < 4; ++j)
                #pragma unroll
                for (int r = 0; r < 4; ++r) {
                    const int t = bm + wm * 64 + i * 16 + (l >> 4) * 4 + r;
                    const int o = bn + wn * 64 + j * 16 + (l & 15);
                    const int head = o >> 6, dd = o & 63;
                    const int k = t & 63;
                    const int slot = (k & 32) | (((k >> 2) & 3) << 3)
                                   | (((k >> 4) & 1) << 2) | (k & 3);
                    vt16[((size_t)(head * HD + dd)) * TT + (t & ~63) + slot] = f2bf(acc[i][j][r]);
                }
    }
}

// ---------------------------------------------------------------------------
// Final projection GEMM: out = y Wo^T, fp32 out [T][C].
// ---------------------------------------------------------------------------
__global__ __launch_bounds__(256) void gemm_out(
    const ushortT* __restrict__ A, const ushortT* __restrict__ B,
    float* __restrict__ dout)
{
    __shared__ char lds[49152];

    const int lin = (int)(blockIdx.y * gridDim.x + blockIdx.x);
    const int nwg8 = (int)((gridDim.x * gridDim.y) >> 3);
    const int swz = (lin & 7) * nwg8 + (lin >> 3);
    const int bm = (swz % (int)gridDim.x) * 128;
    const int bn = (swz / (int)gridDim.x) * 128;
    const int tid = threadIdx.x;
    const int w = tid >> 6, l = tid & 63;
    const int wm = w >> 1, wn = w & 1;

    f32x4 acc[4][4] = {};

    auto stageg = [&](int kk, int base) {
        #pragma unroll
        for (int e = 0; e < 2; ++e) {
            const int D = (w * 2 + e) * 1024 + l * 16;
            const int r = D >> 6;
            const int c = (D & 63) >> 1;
            GLOAD_LDS16(A + (size_t)(bm + r) * CC + kk + c, lds + base + (w * 2 + e) * 1024);
            GLOAD_LDS16(B + (size_t)(bn + r) * CC + kk + c, lds + base + 8192 + (w * 2 + e) * 1024);
        }
    };

    stageg(0, 0);
    stageg(32, 16384);

    for (int kt = 0; kt < 32; ++kt) {
        const int cur = kt % 3;
        if (kt + 2 < 32) {
            stageg((kt + 2) * 32, ((kt + 2) % 3) * 16384);
            asm volatile("s_waitcnt vmcnt(8)" ::: "memory");
        } else if (kt + 1 < 32) {
            asm volatile("s_waitcnt vmcnt(4)" ::: "memory");
        } else {
            asm volatile("s_waitcnt vmcnt(0)" ::: "memory");
        }
        __builtin_amdgcn_s_barrier();
        __builtin_amdgcn_sched_barrier(0);

        const ushortT* As = (const ushortT*)(lds + cur * 16384);
        const ushortT* Bs = (const ushortT*)(lds + cur * 16384 + 8192);

        short8 af[4], bfr[4];
        #pragma unroll
        for (int i = 0; i < 4; ++i) {
            int row = wm * 64 + i * 16 + (l & 15);
            af[i] = *(const short8*)(As + row * 32 + (l >> 4) * 8);
        }
        #pragma unroll
        for (int j = 0; j < 4; ++j) {
            int row = wn * 64 + j * 16 + (l & 15);
            bfr[j] = *(const short8*)(Bs + row * 32 + (l >> 4) * 8);
        }
        #pragma unroll
        for (int i = 0; i < 4; ++i)
            #pragma unroll
            for (int j = 0; j < 4; ++j)
                acc[i][j] = __builtin_amdgcn_mfma_f32_16x16x32_bf16(af[i], bfr[j], acc[i][j], 0, 0, 0);
        __builtin_amdgcn_s_barrier();
    }

    #pragma unroll
    for (int i = 0; i < 4; ++i)
        #pragma unroll
        for (int j = 0; j < 4; ++j)
            #pragma unroll
            for (int r = 0; r < 4; ++r) {
                const int t = bm + wm * 64 + i * 16 + (l >> 4) * 4 + r;
                const int o = bn + wn * 64 + j * 16 + (l & 15);
                dout[(size_t)t * CC + o] = acc[i][j][r];
            }
}

// ---------------------------------------------------------------------------
// Register-P flash attention (swapped QK^T -> S^T; P never touches LDS).
// Persistent work-stealing, counted-vmcnt 2-phase K/Vt double buffer.
// Lane layout: g = l>>4, q = l&15.  s[kg][r] = S^T[key=kg*16+4g+r][qrow=q].
// PV A-frag = packed register P (V is slot-permuted to match).
// ---------------------------------------------------------------------------
__global__ __launch_bounds__(256) void attn_mfma(
    const ushortT* __restrict__ q16, const ushortT* __restrict__ k16,
    const ushortT* __restrict__ vt16, ushortT* __restrict__ y16,
    char* __restrict__ parts, int* __restrict__ counter)
{
    const int tid = threadIdx.x;
    const int w = tid >> 6, l = tid & 63;
    const int g = l >> 4, q = l & 15;

    __shared__ char lds[32768];            // 2 x (K 8KB + Vt 8KB)

    for (;;) {
        if (tid == 0) {
            int tk0 = atomicAdd(counter, 1);
            *(int*)lds = tk0;
        }
        __syncthreads();
        const int tk = *(const int*)lds;
        __syncthreads();                   // all read before staging overwrites
        if (tk >= NTICK) break;

        const int head = tk / NCHUNK_H;    // head-major: L2-resident K/V
        const int t = tk - head * NCHUNK_H;
        int qb, ci, nsplit;
        if (t < 54)       { qb = 63 - t / 3; ci = t % 3; nsplit = 3; }
        else if (t < 102) { int u = t - 54; qb = 45 - u / 2; ci = u % 2; nsplit = 2; }
        else              { qb = 123 - t; ci = -1; nsplit = 1; }
        const int kb0 = (ci < 0) ? 0 : ci * (qb + 1) / nsplit;
        const int kb1 = (ci < 0) ? qb : (ci + 1) * (qb + 1) / nsplit - 1;

        const int qrow = qb * 64 + w * 16 + q;
        short8 qa[2];
        {
            const ushortT* qp = q16 + ((size_t)head * TT + qrow) * HD + g * 8;
            qa[0] = *(const short8*)(qp);
            qa[1] = *(const short8*)(qp + 32);
        }

        f32x4 yacc[4] = {};
        float m_s = -1e30f, l_s = 0.0f;    // scalar state for q-row q (key-quarter)

        auto stage = [&](int kb, int base) {
            #pragma unroll
            for (int e = 0; e < 2; ++e) {
                const int D = (w * 2 + e) * 1024 + l * 16;
                const int row = D >> 7;
                const int src = D ^ ((row & 7) << 4);
                const int col = (src & 127) >> 1;
                GLOAD_LDS16(k16 + ((size_t)head * TT + (size_t)kb * 64 + row) * HD + col,
                            lds + base + (w * 2 + e) * 1024);
                GLOAD_LDS16(vt16 + ((size_t)head * HD + row) * TT + (size_t)kb * 64 + col,
                            lds + base + 8192 + (w * 2 + e) * 1024);
            }
        };

        int cur = 0;
        stage(kb0, 0);

        for (int kb = kb0; kb <= kb1; ++kb) {
            if (kb + 1 <= kb1) {
                stage(kb + 1, (cur ^ 1) * 16384);
                asm volatile("s_waitcnt vmcnt(4)" ::: "memory");
            } else {
                asm volatile("s_waitcnt vmcnt(0)" ::: "memory");
            }
            __builtin_amdgcn_s_barrier();
            __builtin_amdgcn_sched_barrier(0);

            const char* Ks  = lds + cur * 16384;
            const char* Vts = Ks + 8192;

            // S^T = K Q^T  (A = K-frag row=key(l&15), B = Q-frag col=q(l&15))
            f32x4 s[4] = {};
            __builtin_amdgcn_s_setprio(1);
            #pragma unroll
            for (int ks = 0; ks < 2; ++ks)
                #pragma unroll
                for (int kg = 0; kg < 4; ++kg) {
                    const int key = kg * 16 + q;
                    int b = key * 128 + ks * 64 + g * 16;
                    b ^= (key & 7) << 4;
                    short8 kf = *(const short8*)(Ks + b);
                    s[kg] = __builtin_amdgcn_mfma_f32_16x16x32_bf16(kf, qa[ks], s[kg], 0, 0, 0);
                }
            __builtin_amdgcn_s_setprio(0);

            if (kb == qb) {   // diagonal tile only: key = kb*64+kg*16+4g+r
                #pragma unroll
                for (int kg = 0; kg < 4; ++kg)
                    #pragma unroll
                    for (int r = 0; r < 4; ++r)
                        if (kb * 64 + kg * 16 + 4 * g + r > qrow) s[kg][r] = -1e30f;
            }

            // scalar softmax over this lane's 16 keys (quarter of the row)
            float ilmax = s[0][0];
            #pragma unroll
            for (int kg = 0; kg < 4; ++kg)
                #pragma unroll
                for (int r = 0; r < 4; ++r)
                    ilmax = fmaxf(ilmax, s[kg][r]);

            if (__any(ilmax > m_s + 8.0f)) {
                float mx = ilmax;
                mx = fmaxf(mx, __shfl_xor(mx, 16));
                mx = fmaxf(mx, __shfl_xor(mx, 32));   // row max across 4 groups
                const float mnew = fmaxf(m_s, mx);
                const float al = EXP2F(m_s - mnew);
                m_s = mnew;
                l_s *= al;
                float aly[4];
                #pragma unroll
                for (int r = 0; r < 4; ++r)
                    aly[r] = __shfl(al, 20 * g + r);  // alpha of q-row 4g+r
                #pragma unroll
                for (int dg = 0; dg < 4; ++dg)
                    #pragma unroll
                    for (int r = 0; r < 4; ++r)
                        yacc[dg][r] *= aly[r];
            }

            // P = exp2(s - m); pack into PV A-fragments (register-only)
            unsigned U[4], V[4];
            float ls = 0.0f;
            #pragma unroll
            for (int kg = 0; kg < 4; ++kg) {
                const float p0 = EXP2F(s[kg][0] - m_s);
                const float p1 = EXP2F(s[kg][1] - m_s);
                const float p2 = EXP2F(s[kg][2] - m_s);
                const float p3 = EXP2F(s[kg][3] - m_s);
                ls += (p0 + p1) + (p2 + p3);
                asm("v_cvt_pk_bf16_f32 %0, %1, %2" : "=v"(U[kg]) : "v"(p0), "v"(p1));
                asm("v_cvt_pk_bf16_f32 %0, %1, %2" : "=v"(V[kg]) : "v"(p2), "v"(p3));
            }
            l_s += ls;

            // Y += P V  (A = register P, B = slot-permuted V from LDS)
            __builtin_amdgcn_s_setprio(1);
            #pragma unroll
            for (int ks2 = 0; ks2 < 2; ++ks2) {
                union { unsigned u[4]; short8 s8; } pu;
                pu.u[0] = U[2 * ks2];     pu.u[1] = V[2 * ks2];
                pu.u[2] = U[2 * ks2 + 1]; pu.u[3] = V[2 * ks2 + 1];
                const short8 pa = pu.s8;
                #pragma unroll
                for (int dg = 0; dg < 4; ++dg) {
                    const int dd = dg * 16 + q;
                    int vb = dd * 128 + ks2 * 64 + g * 16;
                    vb ^= (dd & 7) << 4;
                    short8 vf = *(const short8*)(Vts + vb);
                    yacc[dg] = __builtin_amdgcn_mfma_f32_16x16x32_bf16(pa, vf, yacc[dg], 0, 0, 0);
                }
            }
            __builtin_amdgcn_s_setprio(0);
            __builtin_amdgcn_s_barrier();
            cur ^= 1;
        }

        // full row sums across the 4 key-quarters
        l_s += __shfl_xor(l_s, 16);
        l_s += __shfl_xor(l_s, 32);
        // redistribute row stats to yacc rows (row of yacc[dg][r] is 4g+r)
        float lr[4];
        #pragma unroll
        for (int r = 0; r < 4; ++r)
            lr[r] = __shfl(l_s, 20 * g + r);

        if (ci < 0) {
            #pragma unroll
            for (int r = 0; r < 4; ++r) lr[r] = 1.0f / lr[r];
            #pragma unroll
            for (int dg = 0; dg < 4; ++dg)
                #pragma unroll
                for (int r = 0; r < 4; ++r) {
                    const int trow = qb * 64 + w * 16 + 4 * g + r;
                    const int col = head * HD + dg * 16 + q;
                    y16[(size_t)trow * CC + col] = f2bf(yacc[dg][r] * lr[r]);
                }
        } else {
            float mr[4];
            #pragma unroll
            for (int r = 0; r < 4; ++r)
                mr[r] = __shfl(m_s, 20 * g + r);
            const int sidx = head * 102 +
                ((qb >= 46) ? (qb - 46) * 3 + ci : 54 + (qb - 22) * 2 + ci);
            char* pb = parts + (size_t)sidx * PSLOT_BYTES;
            ushortT* yp = (ushortT*)pb;
            float* mp = (float*)(pb + 8192);
            float* lp = (float*)(pb + 8448);
            #pragma unroll
            for (int dg = 0; dg < 4; ++dg)
                #pragma unroll
                for (int r = 0; r < 4; ++r) {
                    const int row = w * 16 + 4 * g + r;
                    yp[row * 64 + dg * 16 + q] = f2bf(yacc[dg][r]);
                }
            if (q == 0) {
                #pragma unroll
                for (int r = 0; r < 4; ++r) {
                    const int row = w * 16 + 4 * g + r;
                    mp[row] = mr[r];
                    lp[row] = lr[r];
                }
            }
        }
    }
}

// ---------------------------------------------------------------------------
// Merge 2 or 3 partial chunks for qb in [22, 64).
// ---------------------------------------------------------------------------
__global__ __launch_bounds__(256) void attn_combine(
    const char* __restrict__ parts, ushortT* __restrict__ y16)
{
    const int qb = 22 + blockIdx.x;        // 22..63
    const int head = blockIdx.y;
    const int nsplit = (qb >= 46) ? 3 : 2;
    const int base = head * 102 + ((qb >= 46) ? (qb - 46) * 3 : 54 + (qb - 22) * 2);
    const int row = threadIdx.x >> 2;
    const int pc = threadIdx.x & 3;

    float m_i[3], l_i[3];
    float M = -1e30f;
    for (int i = 0; i < nsplit; ++i) {
        const char* pb = parts + (size_t)(base + i) * PSLOT_BYTES;
        m_i[i] = *(const float*)(pb + 8192 + row * 4);
        l_i[i] = *(const float*)(pb + 8448 + row * 4);
        M = fmaxf(M, m_i[i]);
    }
    float wgt[3], L = 0.0f;
    for (int i = 0; i < nsplit; ++i) {
        wgt[i] = EXP2F(m_i[i] - M);
        L += l_i[i] * wgt[i];
    }
    const float Linv = 1.0f / L;

    const int trow = qb * 64 + row;
    #pragma unroll
    for (int j = 0; j < 16; ++j) {
        const int col = pc * 16 + j;
        float acc = 0.0f;
        for (int i = 0; i < nsplit; ++i) {
            const ushortT* yp = (const ushortT*)(parts + (size_t)(base + i) * PSLOT_BYTES);
            acc += bf2f(yp[row * 64 + col]) * wgt[i];
        }
        y16[(size_t)trow * CC + head * HD + col] = f2bf(acc * Linv);
    }
}

extern "C" void kernel_launch(void* const* d_in, const int* in_sizes, int n_in,
                              void* d_out, int out_size, void* d_ws, size_t ws_size,
                              hipStream_t stream) {
    const float* x    = (const float*)d_in[0];
    const float* fcos = (const float*)d_in[1];
    const float* fsin = (const float*)d_in[2];
    const float* Wq   = (const float*)d_in[3];
    const float* Wk   = (const float*)d_in[4];
    const float* Wv   = (const float*)d_in[5];
    const float* Wo   = (const float*)d_in[6];
    float* out = (float*)d_out;

    char* ws = (char*)d_ws;
    ushortT* xb  = (ushortT*)(ws);                 // [0,8MB)  dead after QKV GEMMs
    ushortT* wqb = (ushortT*)(ws + (8u << 20));    // dead after QKV GEMM
    ushortT* wkb = (ushortT*)(ws + (10u << 20));
    ushortT* wvb = (ushortT*)(ws + (12u << 20));
    ushortT* wob = (ushortT*)(ws + (14u << 20));   // LIVE until final GEMM
    ushortT* q16 = (ushortT*)(ws + (16u << 20));
    ushortT* k16 = (ushortT*)(ws + (24u << 20));
    ushortT* vt16 = (ushortT*)(ws + (32u << 20));
    ushortT* y16 = (ushortT*)(ws + (40u << 20));
    char* parts = ws;                              // [0, 14.2MB) dead region
    int* counter = (int*)(ws + (14u << 20) - 16);  // after parts, before wob

    cvt_all<<<(TT * CC + 4 * CC * CC) / 4 / 256, 256, 0, stream>>>(
        x, Wq, Wk, Wv, Wo, xb, wqb, wkb, wvb, wob);

    dim3 qkvgrid(TT / 128, CC / 128, 3);
    gemm_qkv<<<qkvgrid, 256, 0, stream>>>(xb, wqb, wkb, wvb, fcos, fsin,
                                          q16, k16, vt16);

    hipMemsetAsync(counter, 0, 4, stream);
    attn_mfma<<<1280, 256, 0, stream>>>(q16, k16, vt16, y16, parts, counter);

    dim3 cgrid(42, NH);
    attn_combine<<<cgrid, 256, 0, stream>>>(parts, y16);

    dim3 ggrid(TT / 128, CC / 128);
    gemm_out<<<ggrid, 256, 0, stream>>>(y16, wob, out);
}

// Round 11
// 143.529 us; speedup vs baseline: 1.1488x; 1.1488x over previous
//
#include <hip/hip_runtime.h>
#include <hip/hip_bf16.h>
#include <math.h>

#define TT 4096
#define CC 1024
#define NH 16
#define HD 64

typedef unsigned short ushortT;
typedef __attribute__((ext_vector_type(8))) short short8;
typedef __attribute__((ext_vector_type(4))) float f32x4;

#define GLOAD_LDS16(gp, lp)                                                   \
    __builtin_amdgcn_global_load_lds(                                         \
        (const __attribute__((address_space(1))) void*)(gp),                  \
        (__attribute__((address_space(3))) void*)(lp), 16, 0, 0)

#define EXP2F(x) __builtin_amdgcn_exp2f(x)   // single v_exp_f32

__device__ __forceinline__ ushortT f2bf(float f) {
    __hip_bfloat16 h = __float2bfloat16(f);
    ushortT u; __builtin_memcpy(&u, &h, 2); return u;
}
__device__ __forceinline__ float bf2f(ushortT u) {
    return __uint_as_float(((unsigned)u) << 16);
}

// Partial slot: y bf16[128][64] (16384B) + m f32[128] (512B) + l f32[128] (512B)
#define PSLOT_BYTES 17408
// qc = 128-row q-chunk, 0..31.  direct qc<=10; split2 qc 11..22; split3 qc 23..31.
// Tickets/head = 27 + 24 + 11 = 62; slots/head = 27 + 24 = 51.
// 16*51*17408 = 13.55MB < 14MB dead region.
#define NCHUNK_H 62
#define NTICK (NCHUNK_H * NH)

// ---------------------------------------------------------------------------
// One fused f32->bf16 conversion over x and the four weights.
// ---------------------------------------------------------------------------
__global__ __launch_bounds__(256) void cvt_all(
    const float* __restrict__ x,  const float* __restrict__ wq,
    const float* __restrict__ wk, const float* __restrict__ wv,
    const float* __restrict__ wo,
    ushortT* __restrict__ xb,  ushortT* __restrict__ wqb,
    ushortT* __restrict__ wkb, ushortT* __restrict__ wvb,
    ushortT* __restrict__ wob)
{
    const int i = (blockIdx.x * 256 + threadIdx.x) * 4;
    const int NX = TT * CC, NW = CC * CC;
    const float* s; ushortT* d; int off;
    if (i < NX)               { s = x;  d = xb;  off = i; }
    else if (i < NX + NW)     { s = wq; d = wqb; off = i - NX; }
    else if (i < NX + 2 * NW) { s = wk; d = wkb; off = i - NX - NW; }
    else if (i < NX + 3 * NW) { s = wv; d = wvb; off = i - NX - 2 * NW; }
    else                      { s = wo; d = wob; off = i - NX - 3 * NW; }
    float4 v = *(const float4*)(s + off);
    *(ushort4*)(d + off) = make_ushort4(f2bf(v.x), f2bf(v.y), f2bf(v.z), f2bf(v.w));
}

// ---------------------------------------------------------------------------
// Fused QKV GEMM: blockIdx.z selects weight + epilogue.
// z=0: Q = RoPE(x Wq^T) * 0.125*log2e -> bf16 [h][T][d]
// z=1: K = RoPE(x Wk^T)              -> bf16 [h][T][d]
// z=2: V^T slot-permuted: slot(k) = (k&32)|(((k>>2)&3)<<3)|(((k>>4)&1)<<2)|(k&3)
//      chosen so attention's register-P IS the PV A-fragment (no shuffles).
// ---------------------------------------------------------------------------
__global__ __launch_bounds__(256) void gemm_qkv(
    const ushortT* __restrict__ A,
    const ushortT* __restrict__ Bq, const ushortT* __restrict__ Bk,
    const ushortT* __restrict__ Bv,
    const float* __restrict__ fcos, const float* __restrict__ fsin,
    ushortT* __restrict__ q16, ushortT* __restrict__ k16,
    ushortT* __restrict__ vt16)
{
    __shared__ char lds[49152];            // 3 x (A 8KB + B 8KB)

    const int z = blockIdx.z;
    const ushortT* B = (z == 0) ? Bq : (z == 1) ? Bk : Bv;

    const int lin = (int)(blockIdx.y * gridDim.x + blockIdx.x);
    const int nwg8 = (int)((gridDim.x * gridDim.y) >> 3);
    const int swz = (lin & 7) * nwg8 + (lin >> 3);
    const int bm = (swz % (int)gridDim.x) * 128;
    const int bn = (swz / (int)gridDim.x) * 128;
    const int tid = threadIdx.x;
    const int w = tid >> 6, l = tid & 63;
    const int wm = w >> 1, wn = w & 1;

    f32x4 acc[4][4] = {};

    auto stageg = [&](int kk, int base) {
        #pragma unroll
        for (int e = 0; e < 2; ++e) {
            const int D = (w * 2 + e) * 1024 + l * 16;
            const int r = D >> 6;
            const int c = (D & 63) >> 1;
            GLOAD_LDS16(A + (size_t)(bm + r) * CC + kk + c, lds + base + (w * 2 + e) * 1024);
            GLOAD_LDS16(B + (size_t)(bn + r) * CC + kk + c, lds + base + 8192 + (w * 2 + e) * 1024);
        }
    };

    stageg(0, 0);
    stageg(32, 16384);

    for (int kt = 0; kt < 32; ++kt) {
        const int cur = kt % 3;
        if (kt + 2 < 32) {
            stageg((kt + 2) * 32, ((kt + 2) % 3) * 16384);
            asm volatile("s_waitcnt vmcnt(8)" ::: "memory");
        } else if (kt + 1 < 32) {
            asm volatile("s_waitcnt vmcnt(4)" ::: "memory");
        } else {
            asm volatile("s_waitcnt vmcnt(0)" ::: "memory");
        }
        __builtin_amdgcn_s_barrier();
        __builtin_amdgcn_sched_barrier(0);

        const ushortT* As = (const ushortT*)(lds + cur * 16384);
        const ushortT* Bs = (const ushortT*)(lds + cur * 16384 + 8192);

        short8 af[4], bfr[4];
        #pragma unroll
        for (int i = 0; i < 4; ++i) {
            int row = wm * 64 + i * 16 + (l & 15);
            af[i] = *(const short8*)(As + row * 32 + (l >> 4) * 8);
        }
        #pragma unroll
        for (int j = 0; j < 4; ++j) {
            int row = wn * 64 + j * 16 + (l & 15);
            bfr[j] = *(const short8*)(Bs + row * 32 + (l >> 4) * 8);
        }
        #pragma unroll
        for (int i = 0; i < 4; ++i)
            #pragma unroll
            for (int j = 0; j < 4; ++j)
                acc[i][j] = __builtin_amdgcn_mfma_f32_16x16x32_bf16(af[i], bfr[j], acc[i][j], 0, 0, 0);
        __builtin_amdgcn_s_barrier();
    }

    if (z < 2) {
        const float rsc = (z == 0) ? 0.18033688011112042f : 1.0f;  // 0.125*log2(e)
        ushortT* dq = (z == 0) ? q16 : k16;
        float* cs = (float*)lds;
        float* sn = (float*)(lds + 16384);
        for (int idx = tid; idx < 128 * 32; idx += 256) {
            int rr = idx >> 5, cc2 = idx & 31;
            cs[idx] = fcos[(size_t)(bm + rr) * 32 + cc2];
            sn[idx] = fsin[(size_t)(bm + rr) * 32 + cc2];
        }
        __syncthreads();
        #pragma unroll
        for (int i = 0; i < 4; ++i)
            #pragma unroll
            for (int j = 0; j < 4; ++j)
                #pragma unroll
                for (int r = 0; r < 4; ++r) {
                    const int lt = wm * 64 + i * 16 + (l >> 4) * 4 + r;
                    const int o = bn + wn * 64 + j * 16 + (l & 15);
                    const float v = acc[i][j][r];
                    const float p = __shfl_xor(v, 1);
                    const int pp = (o & 63) >> 1;
                    const float cv = cs[lt * 32 + pp], sv = sn[lt * 32 + pp];
                    const float outv = ((o & 1) ? (p * sv + v * cv) : (v * cv - p * sv)) * rsc;
                    const int t = bm + lt, head = o >> 6, dd = o & 63;
                    dq[((size_t)head * TT + t) * HD + dd] = f2bf(outv);
                }
    } else {
        #pragma unroll
        for (int i = 0; i < 4; ++i)
            #pragma unroll
            for (int j = 0; j < 4; ++j)
                #pragma unroll
                for (int r = 0; r < 4; ++r) {
                    const int t = bm + wm * 64 + i * 16 + (l >> 4) * 4 + r;
                    const int o = bn + wn * 64 + j * 16 + (l & 15);
                    const int head = o >> 6, dd = o & 63;
                    const int k = t & 63;
                    const int slot = (k & 32) | (((k >> 2) & 3) << 3)
                                   | (((k >> 4) & 1) << 2) | (k & 3);
                    vt16[((size_t)(head * HD + dd)) * TT + (t & ~63) + slot] = f2bf(acc[i][j][r]);
                }
    }
}

// ---------------------------------------------------------------------------
// Final projection GEMM: out = y Wo^T, fp32 out [T][C].
// ---------------------------------------------------------------------------
__global__ __launch_bounds__(256) void gemm_out(
    const ushortT* __restrict__ A, const ushortT* __restrict__ B,
    float* __restrict__ dout)
{
    __shared__ char lds[49152];

    const int lin = (int)(blockIdx.y * gridDim.x + blockIdx.x);
    const int nwg8 = (int)((gridDim.x * gridDim.y) >> 3);
    const int swz = (lin & 7) * nwg8 + (lin >> 3);
    const int bm = (swz % (int)gridDim.x) * 128;
    const int bn = (swz / (int)gridDim.x) * 128;
    const int tid = threadIdx.x;
    const int w = tid >> 6, l = tid & 63;
    const int wm = w >> 1, wn = w & 1;

    f32x4 acc[4][4] = {};

    auto stageg = [&](int kk, int base) {
        #pragma unroll
        for (int e = 0; e < 2; ++e) {
            const int D = (w * 2 + e) * 1024 + l * 16;
            const int r = D >> 6;
            const int c = (D & 63) >> 1;
            GLOAD_LDS16(A + (size_t)(bm + r) * CC + kk + c, lds + base + (w * 2 + e) * 1024);
            GLOAD_LDS16(B + (size_t)(bn + r) * CC + kk + c, lds + base + 8192 + (w * 2 + e) * 1024);
        }
    };

    stageg(0, 0);
    stageg(32, 16384);

    for (int kt = 0; kt < 32; ++kt) {
        const int cur = kt % 3;
        if (kt + 2 < 32) {
            stageg((kt + 2) * 32, ((kt + 2) % 3) * 16384);
            asm volatile("s_waitcnt vmcnt(8)" ::: "memory");
        } else if (kt + 1 < 32) {
            asm volatile("s_waitcnt vmcnt(4)" ::: "memory");
        } else {
            asm volatile("s_waitcnt vmcnt(0)" ::: "memory");
        }
        __builtin_amdgcn_s_barrier();
        __builtin_amdgcn_sched_barrier(0);

        const ushortT* As = (const ushortT*)(lds + cur * 16384);
        const ushortT* Bs = (const ushortT*)(lds + cur * 16384 + 8192);

        short8 af[4], bfr[4];
        #pragma unroll
        for (int i = 0; i < 4; ++i) {
            int row = wm * 64 + i * 16 + (l & 15);
            af[i] = *(const short8*)(As + row * 32 + (l >> 4) * 8);
        }
        #pragma unroll
        for (int j = 0; j < 4; ++j) {
            int row = wn * 64 + j * 16 + (l & 15);
            bfr[j] = *(const short8*)(Bs + row * 32 + (l >> 4) * 8);
        }
        #pragma unroll
        for (int i = 0; i < 4; ++i)
            #pragma unroll
            for (int j = 0; j < 4; ++j)
                acc[i][j] = __builtin_amdgcn_mfma_f32_16x16x32_bf16(af[i], bfr[j], acc[i][j], 0, 0, 0);
        __builtin_amdgcn_s_barrier();
    }

    #pragma unroll
    for (int i = 0; i < 4; ++i)
        #pragma unroll
        for (int j = 0; j < 4; ++j)
            #pragma unroll
            for (int r = 0; r < 4; ++r) {
                const int t = bm + wm * 64 + i * 16 + (l >> 4) * 4 + r;
                const int o = bn + wn * 64 + j * 16 + (l & 15);
                dout[(size_t)t * CC + o] = acc[i][j][r];
            }
}

// ---------------------------------------------------------------------------
// Register-P flash attention, QBLK=128, 8 waves (512 thr), wave owns 16 q-rows.
// Persistent work-stealing over ~equal tickets (all co-resident).
// Counted-vmcnt 2-phase K/Vt double buffer; waves above the diagonal skip.
// Lane layout: g = l>>4, q = l&15.  s[kg][r] = S^T[key=kg*16+4g+r][qrow=q].
// ---------------------------------------------------------------------------
__global__ __launch_bounds__(512) void attn_mfma(
    const ushortT* __restrict__ q16, const ushortT* __restrict__ k16,
    const ushortT* __restrict__ vt16, ushortT* __restrict__ y16,
    char* __restrict__ parts, int* __restrict__ counter)
{
    const int tid = threadIdx.x;
    const int w = tid >> 6, l = tid & 63;
    const int g = l >> 4, q = l & 15;

    __shared__ char lds[32768];            // 2 x (K 8KB + Vt 8KB)

    for (;;) {
        if (tid == 0) {
            int tk0 = atomicAdd(counter, 1);
            *(int*)lds = tk0;
        }
        __syncthreads();
        const int tk = *(const int*)lds;
        __syncthreads();                   // all read before staging overwrites
        if (tk >= NTICK) break;

        const int head = tk / NCHUNK_H;    // head-major: L2-resident K/V
        const int t = tk - head * NCHUNK_H;
        int qc, ci, nsplit;
        if (t < 27)      { qc = 31 - t / 3; ci = t % 3; nsplit = 3; }
        else if (t < 51) { int u = t - 27; qc = 22 - u / 2; ci = u & 1; nsplit = 2; }
        else             { qc = 10 - (t - 51); ci = -1; nsplit = 1; }
        const int ntl = 2 * qc + 2;
        const int kb0 = (ci <= 0) ? 0 : ci * ntl / nsplit;
        const int kb1 = (ci < 0) ? (ntl - 1) : ((ci + 1) * ntl / nsplit - 1);

        const int rowbase = qc * 128 + w * 16;
        const int qrow = rowbase + q;
        short8 qa[2];
        {
            const ushortT* qp = q16 + ((size_t)head * TT + qrow) * HD + g * 8;
            qa[0] = *(const short8*)(qp);
            qa[1] = *(const short8*)(qp + 32);
        }

        f32x4 yacc[4] = {};
        float m_s = -1e30f, l_s = 0.0f;    // scalar state for q-row q (key-quarter)

        // 16 segments of 1KB per tile (K 0..7, Vt 8..15); wave w stages 2.
        auto stage = [&](int kb, int base) {
            #pragma unroll
            for (int e = 0; e < 2; ++e) {
                const int seg = w * 2 + e;
                const int D = seg * 1024 + l * 16;
                if (seg < 8) {
                    const int row = D >> 7;
                    const int src = D ^ ((row & 7) << 4);
                    const int col = (src & 127) >> 1;
                    GLOAD_LDS16(k16 + ((size_t)head * TT + (size_t)kb * 64 + row) * HD + col,
                                lds + base + seg * 1024);
                } else {
                    const int Dv = D - 8192;
                    const int row = Dv >> 7;
                    const int src = Dv ^ ((row & 7) << 4);
                    const int col = (src & 127) >> 1;
                    GLOAD_LDS16(vt16 + ((size_t)head * HD + row) * TT + (size_t)kb * 64 + col,
                                lds + base + seg * 1024);
                }
            }
        };

        int cur = 0;
        stage(kb0, 0);

        for (int kb = kb0; kb <= kb1; ++kb) {
            if (kb + 1 <= kb1) {
                stage(kb + 1, (cur ^ 1) * 16384);
                asm volatile("s_waitcnt vmcnt(2)" ::: "memory");
            } else {
                asm volatile("s_waitcnt vmcnt(0)" ::: "memory");
            }
            __builtin_amdgcn_s_barrier();
            __builtin_amdgcn_sched_barrier(0);

            const bool skip = (kb * 64 > rowbase + 15);   // wave fully above diag
            if (!skip) {
                const char* Ks  = lds + cur * 16384;
                const char* Vts = Ks + 8192;

                // S^T = K Q^T
                f32x4 s[4] = {};
                __builtin_amdgcn_s_setprio(1);
                #pragma unroll
                for (int ks = 0; ks < 2; ++ks)
                    #pragma unroll
                    for (int kg = 0; kg < 4; ++kg) {
                        const int key = kg * 16 + q;
                        int b = key * 128 + ks * 64 + g * 16;
                        b ^= (key & 7) << 4;
                        short8 kf = *(const short8*)(Ks + b);
                        s[kg] = __builtin_amdgcn_mfma_f32_16x16x32_bf16(kf, qa[ks], s[kg], 0, 0, 0);
                    }
                __builtin_amdgcn_s_setprio(0);

                if (kb * 64 + 63 > rowbase) {   // triangular region
                    #pragma unroll
                    for (int kg = 0; kg < 4; ++kg)
                        #pragma unroll
                        for (int r = 0; r < 4; ++r)
                            if (kb * 64 + kg * 16 + 4 * g + r > qrow) s[kg][r] = -1e30f;
                }

                float ilmax = s[0][0];
                #pragma unroll
                for (int kg = 0; kg < 4; ++kg)
                    #pragma unroll
                    for (int r = 0; r < 4; ++r)
                        ilmax = fmaxf(ilmax, s[kg][r]);

                if (__any(ilmax > m_s + 8.0f)) {
                    float mx = ilmax;
                    mx = fmaxf(mx, __shfl_xor(mx, 16));
                    mx = fmaxf(mx, __shfl_xor(mx, 32));   // row max across 4 groups
                    const float mnew = fmaxf(m_s, mx);
                    const float al = EXP2F(m_s - mnew);
                    m_s = mnew;
                    l_s *= al;
                    float aly[4];
                    #pragma unroll
                    for (int r = 0; r < 4; ++r)
                        aly[r] = __shfl(al, 20 * g + r);  // alpha of q-row 4g+r
                    #pragma unroll
                    for (int dg = 0; dg < 4; ++dg)
                        #pragma unroll
                        for (int r = 0; r < 4; ++r)
                            yacc[dg][r] *= aly[r];
                }

                // P = exp2(s - m); pack into PV A-fragments (register-only)
                unsigned U[4], V[4];
                float ls = 0.0f;
                #pragma unroll
                for (int kg = 0; kg < 4; ++kg) {
                    const float p0 = EXP2F(s[kg][0] - m_s);
                    const float p1 = EXP2F(s[kg][1] - m_s);
                    const float p2 = EXP2F(s[kg][2] - m_s);
                    const float p3 = EXP2F(s[kg][3] - m_s);
                    ls += (p0 + p1) + (p2 + p3);
                    asm("v_cvt_pk_bf16_f32 %0, %1, %2" : "=v"(U[kg]) : "v"(p0), "v"(p1));
                    asm("v_cvt_pk_bf16_f32 %0, %1, %2" : "=v"(V[kg]) : "v"(p2), "v"(p3));
                }
                l_s += ls;

                // Y += P V
                __builtin_amdgcn_s_setprio(1);
                #pragma unroll
                for (int ks2 = 0; ks2 < 2; ++ks2) {
                    union { unsigned u[4]; short8 s8; } pu;
                    pu.u[0] = U[2 * ks2];     pu.u[1] = V[2 * ks2];
                    pu.u[2] = U[2 * ks2 + 1]; pu.u[3] = V[2 * ks2 + 1];
                    const short8 pa = pu.s8;
                    const char* Vts2 = Vts;
                    #pragma unroll
                    for (int dg = 0; dg < 4; ++dg) {
                        const int dd = dg * 16 + q;
                        int vb = dd * 128 + ks2 * 64 + g * 16;
                        vb ^= (dd & 7) << 4;
                        short8 vf = *(const short8*)(Vts2 + vb);
                        yacc[dg] = __builtin_amdgcn_mfma_f32_16x16x32_bf16(pa, vf, yacc[dg], 0, 0, 0);
                    }
                }
                __builtin_amdgcn_s_setprio(0);
            }
            __builtin_amdgcn_s_barrier();
            cur ^= 1;
        }

        // full row sums across the 4 key-quarters
        l_s += __shfl_xor(l_s, 16);
        l_s += __shfl_xor(l_s, 32);
        float lr[4];
        #pragma unroll
        for (int r = 0; r < 4; ++r)
            lr[r] = __shfl(l_s, 20 * g + r);

        if (ci < 0) {
            #pragma unroll
            for (int r = 0; r < 4; ++r) lr[r] = 1.0f / lr[r];
            #pragma unroll
            for (int dg = 0; dg < 4; ++dg)
                #pragma unroll
                for (int r = 0; r < 4; ++r) {
                    const int trow = rowbase + 4 * g + r;
                    const int col = head * HD + dg * 16 + q;
                    y16[(size_t)trow * CC + col] = f2bf(yacc[dg][r] * lr[r]);
                }
        } else {
            float mr[4];
            #pragma unroll
            for (int r = 0; r < 4; ++r)
                mr[r] = __shfl(m_s, 20 * g + r);
            const int sidx = head * 51 +
                ((qc >= 23) ? (31 - qc) * 3 + ci : 27 + (22 - qc) * 2 + ci);
            char* pb = parts + (size_t)sidx * PSLOT_BYTES;
            ushortT* yp = (ushortT*)pb;
            float* mp = (float*)(pb + 16384);
            float* lp = (float*)(pb + 16896);
            #pragma unroll
            for (int dg = 0; dg < 4; ++dg)
                #pragma unroll
                for (int r = 0; r < 4; ++r) {
                    const int row = w * 16 + 4 * g + r;
                    yp[row * 64 + dg * 16 + q] = f2bf(yacc[dg][r]);
                }
            if (q == 0) {
                #pragma unroll
                for (int r = 0; r < 4; ++r) {
                    const int row = w * 16 + 4 * g + r;
                    mp[row] = mr[r];
                    lp[row] = lr[r];
                }
            }
        }
    }
}

// ---------------------------------------------------------------------------
// Merge 2 or 3 partial chunks for qc in [11, 32).
// ---------------------------------------------------------------------------
__global__ __launch_bounds__(256) void attn_combine(
    const char* __restrict__ parts, ushortT* __restrict__ y16)
{
    const int qc = 11 + blockIdx.x;        // 11..31
    const int head = blockIdx.y;
    const int nsplit = (qc >= 23) ? 3 : 2;
    const int base = head * 51 + ((qc >= 23) ? (31 - qc) * 3 : 27 + (22 - qc) * 2);
    const int tid = threadIdx.x;

    #pragma unroll
    for (int pass = 0; pass < 4; ++pass) {
        const int idx = pass * 2048 + tid * 8;
        const int row = idx >> 6, col = idx & 63;

        float m_i[3], l_i[3];
        float M = -1e30f;
        for (int i = 0; i < nsplit; ++i) {
            const char* pb = parts + (size_t)(base + i) * PSLOT_BYTES;
            m_i[i] = *(const float*)(pb + 16384 + row * 4);
            l_i[i] = *(const float*)(pb + 16896 + row * 4);
            M = fmaxf(M, m_i[i]);
        }
        float wgt[3], L = 0.0f;
        for (int i = 0; i < nsplit; ++i) {
            wgt[i] = EXP2F(m_i[i] - M);
            L += l_i[i] * wgt[i];
        }
        const float Linv = 1.0f / L;

        float acc[8] = {};
        for (int i = 0; i < nsplit; ++i) {
            const ushortT* yp = (const ushortT*)(parts + (size_t)(base + i) * PSLOT_BYTES);
            short8 v = *(const short8*)(yp + row * 64 + col);
            #pragma unroll
            for (int j = 0; j < 8; ++j)
                acc[j] += bf2f((ushortT)v[j]) * wgt[i];
        }
        union { ushortT u[8]; short8 s8; } ov;
        #pragma unroll
        for (int j = 0; j < 8; ++j)
            ov.u[j] = f2bf(acc[j] * Linv);
        const int trow = qc * 128 + row;
        *(short8*)(&y16[(size_t)trow * CC + head * HD + col]) = ov.s8;
    }
}

extern "C" void kernel_launch(void* const* d_in, const int* in_sizes, int n_in,
                              void* d_out, int out_size, void* d_ws, size_t ws_size,
                              hipStream_t stream) {
    const float* x    = (const float*)d_in[0];
    const float* fcos = (const float*)d_in[1];
    const float* fsin = (const float*)d_in[2];
    const float* Wq   = (const float*)d_in[3];
    const float* Wk   = (const float*)d_in[4];
    const float* Wv   = (const float*)d_in[5];
    const float* Wo   = (const float*)d_in[6];
    float* out = (float*)d_out;

    char* ws = (char*)d_ws;
    ushortT* xb  = (ushortT*)(ws);                 // [0,8MB)  dead after QKV GEMMs
    ushortT* wqb = (ushortT*)(ws + (8u << 20));    // dead after QKV GEMM
    ushortT* wkb = (ushortT*)(ws + (10u << 20));
    ushortT* wvb = (ushortT*)(ws + (12u << 20));
    ushortT* wob = (ushortT*)(ws + (14u << 20));   // LIVE until final GEMM
    ushortT* q16 = (ushortT*)(ws + (16u << 20));
    ushortT* k16 = (ushortT*)(ws + (24u << 20));
    ushortT* vt16 = (ushortT*)(ws + (32u << 20));
    ushortT* y16 = (ushortT*)(ws + (40u << 20));
    char* parts = ws;                              // [0, 13.55MB) dead region
    int* counter = (int*)(ws + (14u << 20) - 16);  // just below wob

    cvt_all<<<(TT * CC + 4 * CC * CC) / 4 / 256, 256, 0, stream>>>(
        x, Wq, Wk, Wv, Wo, xb, wqb, wkb, wvb, wob);

    dim3 qkvgrid(TT / 128, CC / 128, 3);
    gemm_qkv<<<qkvgrid, 256, 0, stream>>>(xb, wqb, wkb, wvb, fcos, fsin,
                                          q16, k16, vt16);

    hipMemsetAsync(counter, 0, 4, stream);
    attn_mfma<<<1024, 512, 0, stream>>>(q16, k16, vt16, y16, parts, counter);

    dim3 cgrid(21, NH);
    attn_combine<<<cgrid, 256, 0, stream>>>(parts, y16);

    dim3 ggrid(TT / 128, CC / 128);
    gemm_out<<<ggrid, 256, 0, stream>>>(y16, wob, out);
}